// Round 8
// baseline (1734.633 us; speedup 1.0000x reference)
//
#include <hip/hip_runtime.h>

#define B_    32
#define SSRC  128
#define STGT  64
#define E_    256
#define H_    512
#define G4    2048
#define V_    32000

typedef unsigned short u16;
typedef unsigned long long u64b;
typedef short bf16x8 __attribute__((ext_vector_type(8)));
typedef float f32x4 __attribute__((ext_vector_type(4)));

__device__ __forceinline__ u16 f2b(float f) {
  unsigned u = __float_as_uint(f);
  u += 0x7FFFu + ((u >> 16) & 1u);
  return (u16)(u >> 16);
}
__device__ __forceinline__ float b2f(u16 h) {
  return __uint_as_float(((unsigned)h) << 16);
}
__device__ __forceinline__ unsigned pk2(float lo, float hi) {
  return (unsigned)f2b(lo) | (((unsigned)f2b(hi)) << 16);
}
__device__ __forceinline__ float sigm(float x) { return 1.0f / (1.0f + __expf(-x)); }
__device__ __forceinline__ float tanh_(float x) { return 1.0f - 2.0f / (1.0f + __expf(2.0f * x)); }

#if defined(__has_builtin)
#if __has_builtin(__builtin_amdgcn_fdot2_f32_bf16)
#define HAS_DOT2 1
#endif
#endif
#ifdef HAS_DOT2
typedef __bf16 b162 __attribute__((ext_vector_type(2)));
__device__ __forceinline__ float dot2u(unsigned a, unsigned b, float acc) {
  return __builtin_amdgcn_fdot2_f32_bf16(__builtin_bit_cast(b162, a),
                                         __builtin_bit_cast(b162, b), acc, false);
}
#else
__device__ __forceinline__ float dot2u(unsigned a, unsigned b, float acc) {
  acc += __uint_as_float(a << 16) * __uint_as_float(b << 16);
  acc += __uint_as_float(a & 0xffff0000u) * __uint_as_float(b & 0xffff0000u);
  return acc;
}
#endif
__device__ __forceinline__ float dot4(uint4 w, uint4 h, float acc) {
  return dot2u(w.w, h.w, dot2u(w.z, h.z, dot2u(w.y, h.y, dot2u(w.x, h.x, acc))));
}

__device__ __forceinline__ int swz64(int c) {
  return (c & ~3) | ((c & 3) ^ ((c >> 3) & 3));
}

// ---- device-coherent accesses ----
__device__ __forceinline__ uint4 cload4(const void* p) {
  uint4 r;
  asm volatile("global_load_dwordx4 %0, %1, off sc0 sc1\n\ts_waitcnt vmcnt(0)"
               : "=&v"(r) : "v"(p) : "memory");
  return r;
}
__device__ __forceinline__ void cstoref(float* p, float v) {
  asm volatile("global_store_dword %0, %1, off sc0 sc1" :: "v"(p), "v"(v) : "memory");
}
__device__ __forceinline__ void cstoreu(unsigned* p, unsigned v) {
  asm volatile("global_store_dword %0, %1, off sc0 sc1" :: "v"(p), "v"(v) : "memory");
}
__device__ __forceinline__ float cloadf_relaxed(const float* p) {
  return __hip_atomic_load(p, __ATOMIC_RELAXED, __HIP_MEMORY_SCOPE_AGENT);
}

// ---- split barrier: arrive (drain stores + flag) ... shadow work ... wait ----
__device__ __forceinline__ void arrive(int* flags, int myid, int target) {
  asm volatile("s_waitcnt vmcnt(0)" ::: "memory");
  __syncthreads();
  if (threadIdx.x == 0)
    __hip_atomic_store(flags + myid, target, __ATOMIC_RELAXED, __HIP_MEMORY_SCOPE_AGENT);
}
__device__ __forceinline__ void waitbar(int* flags, int target) {
  if (threadIdx.x < 64) {
    int l = threadIdx.x & 31;
    while (__hip_atomic_load(flags + l, __ATOMIC_RELAXED, __HIP_MEMORY_SCOPE_AGENT) < target)
      __builtin_amdgcn_s_sleep(1);
  }
  __syncthreads();
  asm volatile("" ::: "memory");
}

// ---------------- prep: gathers + bf16 conversions ----------------
__global__ void prep_kernel(const int* __restrict__ src, const int* __restrict__ tgt,
                            const float* __restrict__ enc_emb, const float* __restrict__ dec_emb,
                            const float* __restrict__ enc_Wih, const float* __restrict__ dec_Wih,
                            const float* __restrict__ out_W,
                            u16* __restrict__ A_enc, u16* __restrict__ A_dec,
                            u16* __restrict__ WihE, u16* __restrict__ WihD,
                            u16* __restrict__ WihC, u16* __restrict__ outWb)
{
  const long n_outw = (long)V_ * H_;
  const long n_aenc = (long)B_ * SSRC * E_;
  const long n_adec = (long)B_ * STGT * E_;
  const long n_wih  = (long)G4 * E_;
  const long n_wcp  = (long)G4 * H_;
  const long total = n_outw + n_aenc + n_adec + 2 * n_wih + n_wcp;
  for (long i = (long)blockIdx.x * blockDim.x + threadIdx.x; i < total;
       i += (long)gridDim.x * blockDim.x) {
    long x = i;
    if (x < n_outw) { outWb[x] = f2b(out_W[x]); continue; }
    x -= n_outw;
    if (x < n_aenc) {
      int row = (int)(x >> 8), e = (int)(x & 255);
      A_enc[x] = f2b(enc_emb[(size_t)src[row] * E_ + e]);
      continue;
    }
    x -= n_aenc;
    if (x < n_adec) {
      int row = (int)(x >> 8), e = (int)(x & 255);
      A_dec[x] = f2b(dec_emb[(size_t)tgt[row] * E_ + e]);
      continue;
    }
    x -= n_adec;
    if (x < n_wih) { WihE[x] = f2b(enc_Wih[x]); continue; }
    x -= n_wih;
    if (x < n_wih) {
      int r = (int)(x >> 8), e = (int)(x & 255);
      WihD[x] = f2b(dec_Wih[(size_t)r * 768 + e]);
      continue;
    }
    x -= n_wih;
    {
      int r = (int)(x >> 9), k = (int)(x & 511);
      WihC[x] = f2b(dec_Wih[(size_t)r * 768 + 256 + k]);
    }
  }
}

// ---------------- NT GEMM ----------------
template<int KTOT, bool OBF>
__global__ __launch_bounds__(256, 2) void gemm_nt(
    const u16* __restrict__ A, const u16* __restrict__ Bm,
    const float* __restrict__ bias, void* __restrict__ Cv, int M, int N)
{
  int nbm = M >> 7;
  int bn = blockIdx.x / nbm;
  int bm = blockIdx.x % nbm;
  int w = threadIdx.x >> 6, l = threadIdx.x & 63;
  int wr = w >> 1, wc = w & 1;
  int m0 = bm * 128 + wr * 64, n0 = bn * 128 + wc * 64;
  int lr = l & 15, ko = (l >> 4) * 8;
  f32x4 acc[4][4] = {};
  const u16* Ap = A + (size_t)(m0 + lr) * KTOT + ko;
  const u16* Bp = Bm + (size_t)(n0 + lr) * KTOT + ko;
  for (int k0 = 0; k0 < KTOT; k0 += 32) {
    bf16x8 af[4], bfr[4];
#pragma unroll
    for (int i = 0; i < 4; ++i) af[i] = *(const bf16x8*)(Ap + (size_t)i * 16 * KTOT + k0);
#pragma unroll
    for (int i = 0; i < 4; ++i) bfr[i] = *(const bf16x8*)(Bp + (size_t)i * 16 * KTOT + k0);
#pragma unroll
    for (int i = 0; i < 4; ++i)
#pragma unroll
      for (int j = 0; j < 4; ++j)
        acc[i][j] = __builtin_amdgcn_mfma_f32_16x16x32_bf16(af[i], bfr[j], acc[i][j], 0, 0, 0);
  }
  int rbase = (l >> 4) * 4;
#pragma unroll
  for (int i = 0; i < 4; ++i) {
#pragma unroll
    for (int j = 0; j < 4; ++j) {
      int gn = n0 + j * 16 + lr;
      float bv = bias[gn];
#pragma unroll
      for (int r = 0; r < 4; ++r) {
        int gm = m0 + i * 16 + rbase + r;
        float v = acc[i][j][r] + bv;
        if (OBF) ((u16*)Cv)[(size_t)gm * N + gn] = f2b(v);
        else     ((float*)Cv)[(size_t)gm * N + gn] = v;
      }
    }
  }
}

// ---- shared z-GEMV: 64 gate-rows x 512 k ----
__device__ __forceinline__ void zgemv64(int tid, const uint4* Wu, const uint4* Hu,
                                        float (*part)[64][4]) {
  int rq = tid >> 4, kq = tid & 15;
  float acc[4][4] = {};
#pragma unroll
  for (int u = 0; u < 4; ++u) {
    int sc = swz64(kq * 4 + u);
    uint4 h0 = Hu[sc], h1 = Hu[64 + sc], h2 = Hu[128 + sc], h3 = Hu[192 + sc];
#pragma unroll
    for (int r = 0; r < 4; ++r) {
      uint4 wv = Wu[(rq * 4 + r) * 64 + sc];
      acc[r][0] = dot4(wv, h0, acc[r][0]);
      acc[r][1] = dot4(wv, h1, acc[r][1]);
      acc[r][2] = dot4(wv, h2, acc[r][2]);
      acc[r][3] = dot4(wv, h3, acc[r][3]);
    }
  }
#pragma unroll
  for (int r = 0; r < 4; ++r) {
    float4 v = {acc[r][0], acc[r][1], acc[r][2], acc[r][3]};
    *(float4*)&part[kq][(rq * 4 + r) ^ (kq & 7)][0] = v;
  }
}

template<typename GrowF>
__device__ __forceinline__ void fillw64(int tid, const float* Wsrc, uint4* Wu, GrowF grow) {
#pragma unroll 4
  for (int i = 0; i < 16; ++i) {
    int idx4 = tid + i * 256;
    int row = idx4 >> 6, c = idx4 & 63;
    const float* s = Wsrc + (size_t)grow(row) * 512 + c * 8;
    float4 a = *(const float4*)s, b4 = *(const float4*)(s + 4);
    uint4 pkv = {pk2(a.x, a.y), pk2(a.z, a.w), pk2(b4.x, b4.y), pk2(b4.z, b4.w)};
    Wu[row * 64 + swz64(c)] = pkv;
  }
}

// ---------------- encoder: persistent, 8 groups x 32 blocks, 1 barrier/step ------
// Shadow work (between arrive and wait): eproj + eoP rows for timestep t-1.
__global__ __launch_bounds__(256, 1) void encoder_kernel(
    const float* __restrict__ enc_Whh, const float* __restrict__ attn_W,
    const u16* __restrict__ WihC, const u16* __restrict__ encXW,
    unsigned* __restrict__ h16buf, float* __restrict__ cfin,
    u16* __restrict__ eprojb, u16* __restrict__ eoPw, int* __restrict__ bars)
{
  const int tid = threadIdx.x;
  const int g = blockIdx.x & 7;
  const int gb = blockIdx.x >> 3;
  const int b0 = g * 4;
  const int ds0 = gb * 16;
  int* flags = bars + g * 64;

  __shared__ uint4 encW4[64 * 64];   // 64 KB
  __shared__ uint4 web4[16 * 64];    // 16 KB (W_e rows ds0..+15, row-XOR swz)
  __shared__ uint4 hl16[4 * 64];     // 4 KB
  __shared__ float part[16][64][4];  // 16 KB
  __shared__ float zx[4][64];
  __shared__ float cS[4][16];

  if (tid < 64) cS[tid >> 4][tid & 15] = 0.f;
  fillw64(tid, enc_Whh, encW4, [&](int row) { return (row >> 4) * 512 + ds0 + (row & 15); });
#pragma unroll
  for (int i = 0; i < 4; ++i) {
    int idx4 = tid + i * 256;
    int row = idx4 >> 6, c = idx4 & 63;
    const float* s = attn_W + (size_t)(ds0 + row) * 1024 + 512 + c * 8;
    float4 a = *(const float4*)s, b4 = *(const float4*)(s + 4);
    uint4 pkv = {pk2(a.x, a.y), pk2(a.z, a.w), pk2(b4.x, b4.y), pk2(b4.z, b4.w)};
    web4[row * 64 + (c ^ (row & 7))] = pkv;
  }
  __syncthreads();

  for (int t = 0; t < SSRC; ++t) {
    // stage h_in(t) = enc_out(t-1)
    {
      int row = tid >> 6, c = tid & 63;
      uint4 v = cload4((const uint4*)h16buf + (size_t)(t & 1) * 2048 + (b0 + row) * 64 + c);
      hl16[row * 64 + swz64(c)] = v;
    }
    __syncthreads();
    zgemv64(tid, encW4, hl16, part);
    __syncthreads();
    {
      int b_l = tid >> 6, rl = tid & 63;
      float z = 0.f;
#pragma unroll
      for (int kq = 0; kq < 16; ++kq) z += part[kq][rl ^ (kq & 7)][b_l];
      int grow = (rl >> 4) * 512 + ds0 + (rl & 15);
      z += b2f(encXW[((size_t)(b0 + b_l) * SSRC + t) * G4 + grow]);
      zx[b_l][rl] = z;
    }
    __syncthreads();
    if (tid < 64) {
      int bl = tid >> 4, jl = tid & 15;
      float iv = zx[bl][jl], fv = zx[bl][16 + jl], gv = zx[bl][32 + jl], ov = zx[bl][48 + jl];
      float cn = sigm(fv) * cS[bl][jl] + sigm(iv) * tanh_(gv);
      float hn = sigm(ov) * tanh_(cn);
      cS[bl][jl] = cn;
      float hn1 = __shfl_down(hn, 1);
      if ((jl & 1) == 0)
        cstoreu(h16buf + (size_t)((t + 1) & 1) * 8192 + (size_t)(b0 + bl) * 256 + gb * 8 + (jl >> 1),
                pk2(hn, hn1));
    }
    arrive(flags, gb, t + 1);
    // ---- shadow: eproj + eoP for timestep t-1 from hl16 ----
    if (t > 0) {
      int tm1 = t - 1;
      {
        int d_l = tid >> 4, b_l = (tid >> 2) & 3, kq4 = tid & 3;
        float acc = 0.f;
#pragma unroll
        for (int u = 0; u < 16; ++u) {
          int c = kq4 * 16 + u;
          acc = dot4(web4[d_l * 64 + (c ^ (d_l & 7))], hl16[b_l * 64 + swz64(c)], acc);
        }
        acc += __shfl_xor(acc, 1);
        acc += __shfl_xor(acc, 2);
        if (kq4 == 0)
          eprojb[(((size_t)(b0 + b_l) * SSRC + tm1) << 9) + ds0 + d_l] = f2b(acc);
      }
      {
        int r = tid >> 2, kq4 = tid & 3;
        int n = (r >> 4) * 512 + ds0 + (r & 15);
        const uint4* wr_ = (const uint4*)(WihC + (size_t)n * 512) + kq4 * 16;
        float a0 = 0.f, a1 = 0.f, a2 = 0.f, a3 = 0.f;
#pragma unroll
        for (int u = 0; u < 16; ++u) {
          uint4 wv = wr_[u];
          int sc = swz64(kq4 * 16 + u);
          a0 = dot4(wv, hl16[sc], a0);
          a1 = dot4(wv, hl16[64 + sc], a1);
          a2 = dot4(wv, hl16[128 + sc], a2);
          a3 = dot4(wv, hl16[192 + sc], a3);
        }
        a0 += __shfl_xor(a0, 1); a0 += __shfl_xor(a0, 2);
        a1 += __shfl_xor(a1, 1); a1 += __shfl_xor(a1, 2);
        a2 += __shfl_xor(a2, 1); a2 += __shfl_xor(a2, 2);
        a3 += __shfl_xor(a3, 1); a3 += __shfl_xor(a3, 2);
        if (kq4 == 0) {
          size_t base = ((size_t)b0 * SSRC + tm1) << 11;
          eoPw[base + n] = f2b(a0);
          eoPw[base + (SSRC << 11) + n] = f2b(a1);
          eoPw[base + (2u * SSRC << 11) + n] = f2b(a2);
          eoPw[base + (3u * SSRC << 11) + n] = f2b(a3);
        }
      }
    }
    waitbar(flags, t + 1);
  }
  // epilogue: eproj + eoP for t=127; cfin
  {
    int row = tid >> 6, c = tid & 63;
    uint4 v = cload4((const uint4*)h16buf + (b0 + row) * 64 + c);
    hl16[row * 64 + swz64(c)] = v;
  }
  __syncthreads();
  {
    int tm1 = SSRC - 1;
    {
      int d_l = tid >> 4, b_l = (tid >> 2) & 3, kq4 = tid & 3;
      float acc = 0.f;
#pragma unroll
      for (int u = 0; u < 16; ++u) {
        int c = kq4 * 16 + u;
        acc = dot4(web4[d_l * 64 + (c ^ (d_l & 7))], hl16[b_l * 64 + swz64(c)], acc);
      }
      acc += __shfl_xor(acc, 1);
      acc += __shfl_xor(acc, 2);
      if (kq4 == 0)
        eprojb[(((size_t)(b0 + b_l) * SSRC + tm1) << 9) + ds0 + d_l] = f2b(acc);
    }
    {
      int r = tid >> 2, kq4 = tid & 3;
      int n = (r >> 4) * 512 + ds0 + (r & 15);
      const uint4* wr_ = (const uint4*)(WihC + (size_t)n * 512) + kq4 * 16;
      float a0 = 0.f, a1 = 0.f, a2 = 0.f, a3 = 0.f;
#pragma unroll
      for (int u = 0; u < 16; ++u) {
        uint4 wv = wr_[u];
        int sc = swz64(kq4 * 16 + u);
        a0 = dot4(wv, hl16[sc], a0);
        a1 = dot4(wv, hl16[64 + sc], a1);
        a2 = dot4(wv, hl16[128 + sc], a2);
        a3 = dot4(wv, hl16[192 + sc], a3);
      }
      a0 += __shfl_xor(a0, 1); a0 += __shfl_xor(a0, 2);
      a1 += __shfl_xor(a1, 1); a1 += __shfl_xor(a1, 2);
      a2 += __shfl_xor(a2, 1); a2 += __shfl_xor(a2, 2);
      a3 += __shfl_xor(a3, 1); a3 += __shfl_xor(a3, 2);
      if (kq4 == 0) {
        size_t base = ((size_t)b0 * SSRC + tm1) << 11;
        eoPw[base + n] = f2b(a0);
        eoPw[base + (SSRC << 11) + n] = f2b(a1);
        eoPw[base + (2u * SSRC << 11) + n] = f2b(a2);
        eoPw[base + (3u * SSRC << 11) + n] = f2b(a3);
      }
    }
  }
  if (tid < 64)
    cfin[(size_t)(b0 + (tid >> 4)) * H_ + ds0 + (tid & 15)] = cS[tid >> 4][tid & 15];
}

// ---------------- decoder: persistent, 2 phases/step ------------------------------
__global__ __launch_bounds__(256, 1) void decoder_kernel(
    const float* __restrict__ dec_Whh, const float* __restrict__ attn_W,
    const float* __restrict__ attn_b, const float* __restrict__ attn_v,
    const u16* __restrict__ eprojb, const u16* __restrict__ decXW,
    const u16* __restrict__ eoPb,
    unsigned* __restrict__ hd16, const float* __restrict__ cfin,
    float* __restrict__ vpart /* f32 [8*32][512] */,
    u16* __restrict__ dech, int* __restrict__ bars)
{
  const int tid = threadIdx.x;
  const int g = blockIdx.x & 7;
  const int gb = blockIdx.x >> 3;
  const int b0 = g * 4;
  const int ds0 = gb * 16;
  int* flags = bars + g * 64;
  int ep_ = 0;

  __shared__ uint4 decW4[64 * 64];   // 64 KB
  __shared__ uint4 Whb4[16 * 64];    // 16 KB
  __shared__ uint4 hl16[4 * 64];     // 4 KB
  __shared__ float part[16][64][4];  // 16 KB
  __shared__ float partE[8][64][4];  // 8 KB
  __shared__ float scoreS[4][128];   // 2 KB
  __shared__ float aS[4][128];       // 2 KB
  __shared__ float zx[4][64];
  __shared__ float qS[4][16];
  __shared__ float cS[4][16];
  __shared__ float vS[16], bS[16];

  if (tid < 64) cS[tid >> 4][tid & 15] = cfin[(size_t)(b0 + (tid >> 4)) * H_ + ds0 + (tid & 15)];
  if (tid < 16) { vS[tid] = attn_v[ds0 + tid]; bS[tid] = attn_b[ds0 + tid]; }
  fillw64(tid, dec_Whh, decW4, [&](int row) { return (row >> 4) * 512 + ds0 + (row & 15); });
#pragma unroll
  for (int i = 0; i < 4; ++i) {
    int idx4 = tid + i * 256;
    int row = idx4 >> 6, c = idx4 & 63;
    const float* s = attn_W + (size_t)(ds0 + row) * 1024 + c * 8;
    float4 a = *(const float4*)s, b4 = *(const float4*)(s + 4);
    uint4 pkv = {pk2(a.x, a.y), pk2(a.z, a.w), pk2(b4.x, b4.y), pk2(b4.z, b4.w)};
    Whb4[row * 64 + (c ^ (row & 7))] = pkv;
  }
  // ---- preload this block's static eoP slice into registers (64 KB/block) ----
  const int sq = tid >> 5, cp = tid & 31;
  const int n32 = (cp >> 3) * 256 + gb * 8 + (cp & 7);
  uint4 eor[16];
  {
    const unsigned* eoPu = (const unsigned*)eoPb;
#pragma unroll
    for (int si = 0; si < 16; ++si) {
      int s = sq * 16 + si;
      eor[si].x = eoPu[((size_t)(b0 + 0) * SSRC + s) * 1024 + n32];
      eor[si].y = eoPu[((size_t)(b0 + 1) * SSRC + s) * 1024 + n32];
      eor[si].z = eoPu[((size_t)(b0 + 2) * SSRC + s) * 1024 + n32];
      eor[si].w = eoPu[((size_t)(b0 + 3) * SSRC + s) * 1024 + n32];
    }
  }
  __syncthreads();

  for (int t = 0; t < STGT; ++t) {
    // ==== Phase 1: stage h; local q-slice; energy d-partials; publish; shadow=zgemv ====
    {
      int row = tid >> 6, c = tid & 63;
      uint4 v = cload4((const uint4*)hd16 + (b0 + row) * 64 + c);
      hl16[row * 64 + swz64(c)] = v;
    }
    __syncthreads();
    {
      int b_l = tid >> 6, d_l = (tid >> 2) & 15, kq4 = tid & 3;
      float acc = 0.f;
#pragma unroll
      for (int u = 0; u < 16; ++u) {
        int c = kq4 * 16 + u;
        acc = dot4(Whb4[d_l * 64 + (c ^ (d_l & 7))], hl16[b_l * 64 + swz64(c)], acc);
      }
      acc += __shfl_xor(acc, 1);
      acc += __shfl_xor(acc, 2);
      if (kq4 == 0) qS[b_l][d_l] = acc + bS[d_l];
    }
    __syncthreads();
    {
      float* vp = vpart + ((size_t)g * 32 + gb) * 512;
#pragma unroll
      for (int r = 0; r < 2; ++r) {
        int idx = tid + r * 256;
        int b_l = idx >> 7, s = idx & 127;
        const uint4* ep = (const uint4*)(eprojb + (((size_t)(b0 + b_l) * SSRC + s) << 9) + ds0);
        uint4 e0 = ep[0], e1 = ep[1];
        float acc = 0.f;
        acc += vS[0]  * tanh_(b2f((u16)(e0.x & 0xffff)) + qS[b_l][0]);
        acc += vS[1]  * tanh_(b2f((u16)(e0.x >> 16))    + qS[b_l][1]);
        acc += vS[2]  * tanh_(b2f((u16)(e0.y & 0xffff)) + qS[b_l][2]);
        acc += vS[3]  * tanh_(b2f((u16)(e0.y >> 16))    + qS[b_l][3]);
        acc += vS[4]  * tanh_(b2f((u16)(e0.z & 0xffff)) + qS[b_l][4]);
        acc += vS[5]  * tanh_(b2f((u16)(e0.z >> 16))    + qS[b_l][5]);
        acc += vS[6]  * tanh_(b2f((u16)(e0.w & 0xffff)) + qS[b_l][6]);
        acc += vS[7]  * tanh_(b2f((u16)(e0.w >> 16))    + qS[b_l][7]);
        acc += vS[8]  * tanh_(b2f((u16)(e1.x & 0xffff)) + qS[b_l][8]);
        acc += vS[9]  * tanh_(b2f((u16)(e1.x >> 16))    + qS[b_l][9]);
        acc += vS[10] * tanh_(b2f((u16)(e1.y & 0xffff)) + qS[b_l][10]);
        acc += vS[11] * tanh_(b2f((u16)(e1.y >> 16))    + qS[b_l][11]);
        acc += vS[12] * tanh_(b2f((u16)(e1.z & 0xffff)) + qS[b_l][12]);
        acc += vS[13] * tanh_(b2f((u16)(e1.z >> 16))    + qS[b_l][13]);
        acc += vS[14] * tanh_(b2f((u16)(e1.w & 0xffff)) + qS[b_l][14]);
        acc += vS[15] * tanh_(b2f((u16)(e1.w >> 16))    + qS[b_l][15]);
        cstoref(vp + idx, acc);
      }
    }
    arrive(flags, gb, ++ep_);
    zgemv64(tid, decW4, hl16, part);   // shadow: hides barrier latency
    waitbar(flags, ep_);

    // ==== Phase 2: gather partials -> scores; softmax; eoP-reg z; gates ====
    {
      int b_l = tid >> 6, s0 = (tid & 63) * 2;
      float a0 = 0.f, a1 = 0.f;
#pragma unroll 8
      for (int j = 0; j < 32; ++j) {
        const float* p = vpart + ((size_t)g * 32 + j) * 512 + b_l * 128 + s0;
        a0 += cloadf_relaxed(p);
        a1 += cloadf_relaxed(p + 1);
      }
      scoreS[b_l][s0] = a0;
      scoreS[b_l][s0 + 1] = a1;
    }
    __syncthreads();
    {
      int w = tid >> 6, lane = tid & 63;
      float s1 = scoreS[w][lane], s2v = scoreS[w][64 + lane];
      float m = fmaxf(s1, s2v);
#pragma unroll
      for (int off = 32; off; off >>= 1) m = fmaxf(m, __shfl_xor(m, off));
      float e1 = __expf(s1 - m), e2 = __expf(s2v - m);
      float sm = e1 + e2;
#pragma unroll
      for (int off = 32; off; off >>= 1) sm += __shfl_xor(sm, off);
      float inv = 1.0f / sm;
      aS[w][lane] = e1 * inv;
      aS[w][64 + lane] = e2 * inv;
    }
    __syncthreads();
    {
      float a0 = 0.f, a1 = 0.f, a2 = 0.f, a3 = 0.f, a4 = 0.f, a5 = 0.f, a6 = 0.f, a7 = 0.f;
#pragma unroll
      for (int si = 0; si < 16; ++si) {
        int s = sq * 16 + si;
        float w0 = aS[0][s], w1 = aS[1][s], w2 = aS[2][s], w3 = aS[3][s];
        unsigned u0 = eor[si].x, u1 = eor[si].y, u2 = eor[si].z, u3 = eor[si].w;
        a0 += w0 * b2f((u16)(u0 & 0xffff)); a1 += w0 * b2f((u16)(u0 >> 16));
        a2 += w1 * b2f((u16)(u1 & 0xffff)); a3 += w1 * b2f((u16)(u1 >> 16));
        a4 += w2 * b2f((u16)(u2 & 0xffff)); a5 += w2 * b2f((u16)(u2 >> 16));
        a6 += w3 * b2f((u16)(u3 & 0xffff)); a7 += w3 * b2f((u16)(u3 >> 16));
      }
      int r0 = (cp >> 3) * 16 + (cp & 7) * 2;
      float4 lo = {a0, a2, a4, a6}, hi = {a1, a3, a5, a7};
      *(float4*)&partE[sq][r0][0] = lo;
      *(float4*)&partE[sq][r0 + 1][0] = hi;
    }
    __syncthreads();
    {
      int b_l = tid >> 6, rl = tid & 63;
      float z = 0.f;
#pragma unroll
      for (int kq = 0; kq < 16; ++kq) z += part[kq][rl ^ (kq & 7)][b_l];
#pragma unroll
      for (int sq2 = 0; sq2 < 8; ++sq2) z += partE[sq2][rl][b_l];
      int grow = (rl >> 4) * 512 + ds0 + (rl & 15);
      z += b2f(decXW[((size_t)(b0 + b_l) * STGT + t) * G4 + grow]);
      zx[b_l][rl] = z;
    }
    __syncthreads();
    if (tid < 64) {
      int bl = tid >> 4, jl = tid & 15;
      float iv = zx[bl][jl], fv = zx[bl][16 + jl], gv = zx[bl][32 + jl], ov = zx[bl][48 + jl];
      float cn = sigm(fv) * cS[bl][jl] + sigm(iv) * tanh_(gv);
      float hn = sigm(ov) * tanh_(cn);
      cS[bl][jl] = cn;
      dech[((size_t)(b0 + bl) * STGT + t) * H_ + ds0 + jl] = f2b(hn);
      float hn1 = __shfl_down(hn, 1);
      if ((jl & 1) == 0)
        cstoreu(hd16 + (size_t)(b0 + bl) * 256 + gb * 8 + (jl >> 1), pk2(hn, hn1));
    }
    arrive(flags, gb, ++ep_);
    waitbar(flags, ep_);
  }
}

// ---------------- workspace layout (bytes) ----------------
#define OFF_BARE   0u
#define OFF_BARD   2048u
#define OFF_H16    4096u        // u32 [2][32][256] = 64 KB
#define OFF_CFIN   69632u       // 64 KB
#define OFF_VPART  135168u      // f32 [256][512] = 512 KB
#define OFF_AENC   1048576u     // 2 MB
#define OFF_ADEC   3145728u     // 1 MB
#define OFF_WIHE   4194304u     // 1 MB
#define OFF_WIHD   5242880u     // 1 MB
#define OFF_WIHC   6291456u     // 2 MB
#define OFF_OUTW   8388608u     // 32.77 MB
#define OFF_ENCXW  41943040u    // 16.78 MB  [aliased by eoP, column-disjoint]
#define OFF_DECXW  58720256u    // 8.39 MB
#define OFF_EPROJ  67108864u    // 4.19 MB
#define OFF_DECH   71303168u    // 2.10 MB -> end 73.4 MB

extern "C" void kernel_launch(void* const* d_in, const int* in_sizes, int n_in,
                              void* d_out, int out_size, void* d_ws, size_t ws_size,
                              hipStream_t stream)
{
  const int*   src     = (const int*)d_in[0];
  const int*   tgt     = (const int*)d_in[1];
  const float* enc_emb = (const float*)d_in[2];
  const float* enc_Wih = (const float*)d_in[3];
  const float* enc_Whh = (const float*)d_in[4];
  const float* enc_b   = (const float*)d_in[5];
  const float* attn_W  = (const float*)d_in[6];
  const float* attn_b  = (const float*)d_in[7];
  const float* attn_v  = (const float*)d_in[8];
  const float* dec_emb = (const float*)d_in[9];
  const float* dec_Wih = (const float*)d_in[10];
  const float* dec_Whh = (const float*)d_in[11];
  const float* dec_b   = (const float*)d_in[12];
  const float* out_W   = (const float*)d_in[13];
  const float* out_b   = (const float*)d_in[14];

  char* ws = (char*)d_ws;
  int*      barE   = (int*)(ws + OFF_BARE);
  int*      barD   = (int*)(ws + OFF_BARD);
  unsigned* h16buf = (unsigned*)(ws + OFF_H16);
  float*    cfin   = (float*)(ws + OFF_CFIN);
  float*    vpart  = (float*)(ws + OFF_VPART);
  u16*      A_enc  = (u16*)(ws + OFF_AENC);
  u16*      A_dec  = (u16*)(ws + OFF_ADEC);
  u16*      WihE   = (u16*)(ws + OFF_WIHE);
  u16*      WihD   = (u16*)(ws + OFF_WIHD);
  u16*      WihC   = (u16*)(ws + OFF_WIHC);
  u16*      outWb  = (u16*)(ws + OFF_OUTW);
  u16*      encXW  = (u16*)(ws + OFF_ENCXW);
  u16*      eoPb   = (u16*)(ws + OFF_ENCXW);   // alias: column-disjoint, write-after-read
  u16*      decXW  = (u16*)(ws + OFF_DECXW);
  u16*      eprojb = (u16*)(ws + OFF_EPROJ);
  u16*      dech   = (u16*)(ws + OFF_DECH);

  (void)hipMemsetAsync(d_ws, 0, OFF_H16 + 65536, stream);

  prep_kernel<<<2048, 256, 0, stream>>>(src, tgt, enc_emb, dec_emb, enc_Wih, dec_Wih,
                                        out_W, A_enc, A_dec, WihE, WihD, WihC, outWb);

  // encXW = emb_src @ enc_Wih^T + enc_b   (4096 x 2048 x 256) -> bf16
  gemm_nt<256, true><<<512, 256, 0, stream>>>(A_enc, WihE, enc_b, (void*)encXW, 4096, 2048);
  // decXW = emb_tgt @ dec_Wih[:, :E]^T + dec_b  (2048 x 2048 x 256) -> bf16
  gemm_nt<256, true><<<256, 256, 0, stream>>>(A_dec, WihD, dec_b, (void*)decXW, 2048, 2048);

  // encoder recurrence + inline eproj/eoP
  encoder_kernel<<<256, 256, 0, stream>>>(enc_Whh, attn_W, WihC, encXW,
                                          h16buf, cfin, eprojb, eoPb, barE);

  // decoder recurrence (2 phases/step)
  decoder_kernel<<<256, 256, 0, stream>>>(dec_Whh, attn_W, attn_b, attn_v,
                                          eprojb, decXW, eoPb, h16buf, cfin,
                                          vpart, dech, barD);

  // out = dec_h @ out_W^T + out_b  (2048 x 32000 x 512) -> f32
  gemm_nt<512, false><<<4000, 256, 0, stream>>>(dech, outWb, out_b, d_out, 2048, 32000);
}

// Round 9
// 1654.758 us; speedup vs baseline: 1.0483x; 1.0483x over previous
//
#include <hip/hip_runtime.h>

#define B_    32
#define SSRC  128
#define STGT  64
#define E_    256
#define H_    512
#define G4    2048
#define V_    32000

typedef unsigned short u16;
typedef unsigned long long u64b;
typedef short bf16x8 __attribute__((ext_vector_type(8)));
typedef float f32x4 __attribute__((ext_vector_type(4)));

__device__ __forceinline__ u16 f2b(float f) {
  unsigned u = __float_as_uint(f);
  u += 0x7FFFu + ((u >> 16) & 1u);
  return (u16)(u >> 16);
}
__device__ __forceinline__ float b2f(u16 h) {
  return __uint_as_float(((unsigned)h) << 16);
}
__device__ __forceinline__ unsigned pk2(float lo, float hi) {
  return (unsigned)f2b(lo) | (((unsigned)f2b(hi)) << 16);
}
__device__ __forceinline__ float sigm(float x) { return 1.0f / (1.0f + __expf(-x)); }
__device__ __forceinline__ float tanh_(float x) { return 1.0f - 2.0f / (1.0f + __expf(2.0f * x)); }

#if defined(__has_builtin)
#if __has_builtin(__builtin_amdgcn_fdot2_f32_bf16)
#define HAS_DOT2 1
#endif
#endif
#ifdef HAS_DOT2
typedef __bf16 b162 __attribute__((ext_vector_type(2)));
__device__ __forceinline__ float dot2u(unsigned a, unsigned b, float acc) {
  return __builtin_amdgcn_fdot2_f32_bf16(__builtin_bit_cast(b162, a),
                                         __builtin_bit_cast(b162, b), acc, false);
}
#else
__device__ __forceinline__ float dot2u(unsigned a, unsigned b, float acc) {
  acc += __uint_as_float(a << 16) * __uint_as_float(b << 16);
  acc += __uint_as_float(a & 0xffff0000u) * __uint_as_float(b & 0xffff0000u);
  return acc;
}
#endif
__device__ __forceinline__ float dot4(uint4 w, uint4 h, float acc) {
  return dot2u(w.w, h.w, dot2u(w.z, h.z, dot2u(w.y, h.y, dot2u(w.x, h.x, acc))));
}

__device__ __forceinline__ int swz64(int c) {
  return (c & ~3) | ((c & 3) ^ ((c >> 3) & 3));
}

// ---- epoch-tagged exchange: u64 = {tag:32 | payload:32}, single atomic store ----
__device__ __forceinline__ void tstore(u64b* p, unsigned payload, unsigned tag) {
  __hip_atomic_store(p, ((u64b)tag << 32) | payload, __ATOMIC_RELAXED, __HIP_MEMORY_SCOPE_AGENT);
}
__device__ __forceinline__ u64b tload(const u64b* p) {
  return __hip_atomic_load(p, __ATOMIC_RELAXED, __HIP_MEMORY_SCOPE_AGENT);
}
__device__ __forceinline__ void poll4(const u64b* p, unsigned tag,
                                      u64b& a, u64b& b, u64b& c, u64b& d) {
  for (;;) {
    a = tload(p + 0); b = tload(p + 1); c = tload(p + 2); d = tload(p + 3);
    if ((((unsigned)(a >> 32)) == tag) & (((unsigned)(b >> 32)) == tag) &
        (((unsigned)(c >> 32)) == tag) & (((unsigned)(d >> 32)) == tag)) return;
    __builtin_amdgcn_s_sleep(1);
  }
}
__device__ __forceinline__ void poll8(const u64b* p, unsigned tag,
                                      u64b& a, u64b& b, u64b& c, u64b& d,
                                      u64b& e, u64b& f, u64b& g_, u64b& h) {
  for (;;) {
    a = tload(p + 0); b = tload(p + 1); c = tload(p + 2); d = tload(p + 3);
    e = tload(p + 4); f = tload(p + 5); g_ = tload(p + 6); h = tload(p + 7);
    if ((((unsigned)(a >> 32)) == tag) & (((unsigned)(b >> 32)) == tag) &
        (((unsigned)(c >> 32)) == tag) & (((unsigned)(d >> 32)) == tag) &
        (((unsigned)(e >> 32)) == tag) & (((unsigned)(f >> 32)) == tag) &
        (((unsigned)(g_ >> 32)) == tag) & (((unsigned)(h >> 32)) == tag)) return;
    __builtin_amdgcn_s_sleep(1);
  }
}

// ---------------- prep: gathers + bf16 conversions ----------------
__global__ void prep_kernel(const int* __restrict__ src, const int* __restrict__ tgt,
                            const float* __restrict__ enc_emb, const float* __restrict__ dec_emb,
                            const float* __restrict__ enc_Wih, const float* __restrict__ dec_Wih,
                            const float* __restrict__ attn_W, const float* __restrict__ out_W,
                            u16* __restrict__ A_enc, u16* __restrict__ A_dec,
                            u16* __restrict__ WihE, u16* __restrict__ WihD,
                            u16* __restrict__ Web, u16* __restrict__ WihCp,
                            u16* __restrict__ outWb)
{
  const long n_outw = (long)V_ * H_;
  const long n_aenc = (long)B_ * SSRC * E_;
  const long n_adec = (long)B_ * STGT * E_;
  const long n_wih  = (long)G4 * E_;
  const long n_web  = (long)H_ * H_;
  const long n_wcp  = (long)G4 * H_;
  const long total = n_outw + n_aenc + n_adec + 2 * n_wih + n_web + n_wcp;
  for (long i = (long)blockIdx.x * blockDim.x + threadIdx.x; i < total;
       i += (long)gridDim.x * blockDim.x) {
    long x = i;
    if (x < n_outw) { outWb[x] = f2b(out_W[x]); continue; }
    x -= n_outw;
    if (x < n_aenc) {
      int row = (int)(x >> 8), e = (int)(x & 255);
      A_enc[x] = f2b(enc_emb[(size_t)src[row] * E_ + e]);
      continue;
    }
    x -= n_aenc;
    if (x < n_adec) {
      int row = (int)(x >> 8), e = (int)(x & 255);
      A_dec[x] = f2b(dec_emb[(size_t)tgt[row] * E_ + e]);
      continue;
    }
    x -= n_adec;
    if (x < n_wih) { WihE[x] = f2b(enc_Wih[x]); continue; }
    x -= n_wih;
    if (x < n_wih) {
      int r = (int)(x >> 8), e = (int)(x & 255);
      WihD[x] = f2b(dec_Wih[(size_t)r * 768 + e]);
      continue;
    }
    x -= n_wih;
    if (x < n_web) {
      int d = (int)(x >> 9), k = (int)(x & 511);
      Web[x] = f2b(attn_W[(size_t)d * 1024 + 512 + k]);
      continue;
    }
    x -= n_web;
    {
      // permuted WihC rows: n = gb*64 + gate*16 + jl  ->  orig gate*512 + gb*16 + jl
      int n = (int)(x >> 9), k = (int)(x & 511);
      int gb = n >> 6, gate = (n >> 4) & 3, jl = n & 15;
      int orig = gate * 512 + gb * 16 + jl;
      WihCp[x] = f2b(dec_Wih[(size_t)orig * 768 + 256 + k]);
    }
  }
}

// ---------------- NT GEMM: C[m][n] = sum_k A[m][k]*B[n][k] + bias[n] ----------------
template<int KTOT, bool OBF>
__global__ __launch_bounds__(256, 2) void gemm_nt(
    const u16* __restrict__ A, const u16* __restrict__ Bm,
    const float* __restrict__ bias, void* __restrict__ Cv, int M, int N)
{
  int nbm = M >> 7;
  int bn = blockIdx.x / nbm;
  int bm = blockIdx.x % nbm;
  int w = threadIdx.x >> 6, l = threadIdx.x & 63;
  int wr = w >> 1, wc = w & 1;
  int m0 = bm * 128 + wr * 64, n0 = bn * 128 + wc * 64;
  int lr = l & 15, ko = (l >> 4) * 8;
  f32x4 acc[4][4] = {};
  const u16* Ap = A + (size_t)(m0 + lr) * KTOT + ko;
  const u16* Bp = Bm + (size_t)(n0 + lr) * KTOT + ko;
  for (int k0 = 0; k0 < KTOT; k0 += 32) {
    bf16x8 af[4], bfr[4];
#pragma unroll
    for (int i = 0; i < 4; ++i) af[i] = *(const bf16x8*)(Ap + (size_t)i * 16 * KTOT + k0);
#pragma unroll
    for (int i = 0; i < 4; ++i) bfr[i] = *(const bf16x8*)(Bp + (size_t)i * 16 * KTOT + k0);
#pragma unroll
    for (int i = 0; i < 4; ++i)
#pragma unroll
      for (int j = 0; j < 4; ++j)
        acc[i][j] = __builtin_amdgcn_mfma_f32_16x16x32_bf16(af[i], bfr[j], acc[i][j], 0, 0, 0);
  }
  int rbase = (l >> 4) * 4;
#pragma unroll
  for (int i = 0; i < 4; ++i) {
#pragma unroll
    for (int j = 0; j < 4; ++j) {
      int gn = n0 + j * 16 + lr;
      float bv = bias ? bias[gn] : 0.f;
#pragma unroll
      for (int r = 0; r < 4; ++r) {
        int gm = m0 + i * 16 + rbase + r;
        float v = acc[i][j][r] + bv;
        if (OBF) ((u16*)Cv)[(size_t)gm * N + gn] = f2b(v);
        else     ((float*)Cv)[(size_t)gm * N + gn] = v;
      }
    }
  }
}

// ---- shared z-GEMV: 64 gate-rows x 512 k, bf16, swizzled LDS ----
__device__ __forceinline__ void zgemv64(int tid, const uint4* Wu, const uint4* Hu,
                                        float (*part)[64][4]) {
  int rq = tid >> 4, kq = tid & 15;
  float acc[4][4] = {};
#pragma unroll
  for (int u = 0; u < 4; ++u) {
    int sc = swz64(kq * 4 + u);
    uint4 h0 = Hu[sc], h1 = Hu[64 + sc], h2 = Hu[128 + sc], h3 = Hu[192 + sc];
#pragma unroll
    for (int r = 0; r < 4; ++r) {
      uint4 wv = Wu[(rq * 4 + r) * 64 + sc];
      acc[r][0] = dot4(wv, h0, acc[r][0]);
      acc[r][1] = dot4(wv, h1, acc[r][1]);
      acc[r][2] = dot4(wv, h2, acc[r][2]);
      acc[r][3] = dot4(wv, h3, acc[r][3]);
    }
  }
#pragma unroll
  for (int r = 0; r < 4; ++r) {
    float4 v = {acc[r][0], acc[r][1], acc[r][2], acc[r][3]};
    *(float4*)&part[kq][(rq * 4 + r) ^ (kq & 7)][0] = v;
  }
}

template<typename GrowF>
__device__ __forceinline__ void fillw64(int tid, const float* Wsrc, uint4* Wu, GrowF grow) {
#pragma unroll 4
  for (int i = 0; i < 16; ++i) {
    int idx4 = tid + i * 256;
    int row = idx4 >> 6, c = idx4 & 63;
    const float* s = Wsrc + (size_t)grow(row) * 512 + c * 8;
    float4 a = *(const float4*)s, b4 = *(const float4*)(s + 4);
    uint4 pkv = {pk2(a.x, a.y), pk2(a.z, a.w), pk2(b4.x, b4.y), pk2(b4.z, b4.w)};
    Wu[row * 64 + swz64(c)] = pkv;
  }
}

// ---------------- encoder: persistent, tagged h exchange, NO barriers ----------------
__global__ __launch_bounds__(256, 1) void encoder_kernel(
    const float* __restrict__ enc_Whh, const u16* __restrict__ encXW,
    u64b* __restrict__ hbufE /* [2][32][256] */, u64b* __restrict__ hd64 /* [32][256] */,
    float* __restrict__ cfin, u16* __restrict__ eo_g)
{
  const int tid = threadIdx.x;
  const int g = blockIdx.x & 7;
  const int gb = blockIdx.x >> 3;
  const int b0 = g * 4;
  const int ds0 = gb * 16;

  __shared__ uint4 encW4[64 * 64];   // 64 KB
  __shared__ uint4 hl16[4 * 64];     // 4 KB
  __shared__ float part[16][64][4];  // 16 KB
  __shared__ float zx[4][64];
  __shared__ float cS[4][16];

  if (tid < 64) cS[tid >> 4][tid & 15] = 0.f;
  fillw64(tid, enc_Whh, encW4, [&](int row) { return (row >> 4) * 512 + ds0 + (row & 15); });
  __syncthreads();

  for (int t = 0; t < SSRC; ++t) {
    // poll h (tag t, buffer t&1) -> LDS
    {
      int row = tid >> 6, c = tid & 63;
      const u64b* p = hbufE + (size_t)(t & 1) * 8192 + (size_t)(b0 + row) * 256 + c * 4;
      u64b v0, v1, v2, v3;
      poll4(p, (unsigned)t, v0, v1, v2, v3);
      uint4 hv = {(unsigned)v0, (unsigned)v1, (unsigned)v2, (unsigned)v3};
      hl16[row * 64 + swz64(c)] = hv;
    }
    __syncthreads();
    zgemv64(tid, encW4, hl16, part);
    __syncthreads();
    {
      int b_l = tid >> 6, rl = tid & 63;
      float z = 0.f;
#pragma unroll
      for (int kq = 0; kq < 16; ++kq) z += part[kq][rl ^ (kq & 7)][b_l];
      int grow = (rl >> 4) * 512 + ds0 + (rl & 15);
      z += b2f(encXW[((size_t)(b0 + b_l) * SSRC + t) * G4 + grow]);
      zx[b_l][rl] = z;
    }
    __syncthreads();
    if (tid < 64) {
      int bl = tid >> 4, jl = tid & 15;
      float iv = zx[bl][jl], fv = zx[bl][16 + jl], gv = zx[bl][32 + jl], ov = zx[bl][48 + jl];
      float cn = sigm(fv) * cS[bl][jl] + sigm(iv) * tanh_(gv);
      float hn = sigm(ov) * tanh_(cn);
      cS[bl][jl] = cn;
      eo_g[((size_t)(b0 + bl) * SSRC + t) * H_ + ds0 + jl] = f2b(hn);
      float hn1 = __shfl_down(hn, 1);
      if ((jl & 1) == 0) {
        unsigned pk = pk2(hn, hn1);
        size_t w = (size_t)(b0 + bl) * 256 + gb * 8 + (jl >> 1);
        tstore(hbufE + (size_t)((t + 1) & 1) * 8192 + w, pk, (unsigned)(t + 1));
        if (t == SSRC - 1) tstore(hd64 + w, pk, 1u);  // handoff to decoder (tag 1)
      }
    }
    __syncthreads();
  }
  if (tid < 64)
    cfin[(size_t)(b0 + (tid >> 4)) * H_ + ds0 + (tid & 15)] = cS[tid >> 4][tid & 15];
}

// ---------------- decoder: persistent, 3 tagged exchanges/step, NO barriers ---------
__global__ __launch_bounds__(256, 1) void decoder_kernel(
    const float* __restrict__ dec_Whh, const float* __restrict__ attn_W,
    const float* __restrict__ attn_b, const float* __restrict__ attn_v,
    const u16* __restrict__ eprojb, const u16* __restrict__ decXW,
    const u16* __restrict__ eoPb,
    u64b* __restrict__ hd64, const float* __restrict__ cfin,
    u64b* __restrict__ qg64 /* [8][4][512] */, u64b* __restrict__ scoreb64 /* [8][4][128] */,
    u16* __restrict__ dech)
{
  const int tid = threadIdx.x;
  const int g = blockIdx.x & 7;
  const int gb = blockIdx.x >> 3;
  const int b0 = g * 4;
  const int ds0 = gb * 16;

  __shared__ uint4 decW4[64 * 64];   // 64 KB
  __shared__ uint4 Whb4[16 * 64];    // 16 KB
  __shared__ uint4 hl16[4 * 64];     // 4 KB
  __shared__ float part[16][64][4];  // 16 KB
  __shared__ float partE[8][64][4];  // 8 KB
  __shared__ float4 qf4[4 * 128];    // 8 KB
  __shared__ float4 vf4[128];        // 2 KB
  __shared__ float scoreS[4][128];
  __shared__ float aS[4][128];
  __shared__ float zx[4][64];
  __shared__ __align__(16) float qS[4][16];
  __shared__ __align__(16) float scr16[4][4];
  __shared__ float cS[4][16];
  __shared__ float bS[16];

  if (tid < 64) cS[tid >> 4][tid & 15] = cfin[(size_t)(b0 + (tid >> 4)) * H_ + ds0 + (tid & 15)];
  if (tid < 16) bS[tid] = attn_b[ds0 + tid];
  if (tid < 128) {
    float4 v = *(const float4*)(attn_v + tid * 4);
    vf4[tid ^ ((tid >> 3) & 7)] = v;
  }
  fillw64(tid, dec_Whh, decW4, [&](int row) { return (row >> 4) * 512 + ds0 + (row & 15); });
#pragma unroll
  for (int i = 0; i < 4; ++i) {
    int idx4 = tid + i * 256;
    int row = idx4 >> 6, c = idx4 & 63;
    const float* s = attn_W + (size_t)(ds0 + row) * 1024 + c * 8;
    float4 a = *(const float4*)s, b4 = *(const float4*)(s + 4);
    uint4 pkv = {pk2(a.x, a.y), pk2(a.z, a.w), pk2(b4.x, b4.y), pk2(b4.z, b4.w)};
    Whb4[row * 64 + (c ^ (row & 7))] = pkv;
  }
  __syncthreads();

  for (int t = 0; t < STGT; ++t) {
    // ==== Phase A: poll h (tag t+1); local q-slice; publish q (tag t+1); zgemv shadow ====
    {
      int row = tid >> 6, c = tid & 63;
      const u64b* p = hd64 + (size_t)(b0 + row) * 256 + c * 4;
      u64b v0, v1, v2, v3;
      poll4(p, (unsigned)(t + 1), v0, v1, v2, v3);
      uint4 hv = {(unsigned)v0, (unsigned)v1, (unsigned)v2, (unsigned)v3};
      hl16[row * 64 + swz64(c)] = hv;
    }
    __syncthreads();
    {
      int b_l = tid >> 6, d_l = (tid >> 2) & 15, kq4 = tid & 3;
      float acc = 0.f;
#pragma unroll
      for (int u = 0; u < 16; ++u) {
        int c = kq4 * 16 + u;
        acc = dot4(Whb4[d_l * 64 + (c ^ (d_l & 7))], hl16[b_l * 64 + swz64(c)], acc);
      }
      acc += __shfl_xor(acc, 1);
      acc += __shfl_xor(acc, 2);
      if (kq4 == 0) qS[b_l][d_l] = acc + bS[d_l];
    }
    __syncthreads();
    if (tid < 16) {
      int bl = tid >> 2, i0 = (tid & 3) * 4;
      u64b* qp = qg64 + (size_t)(g * 4 + bl) * 512 + ds0 + i0;
#pragma unroll
      for (int k = 0; k < 4; ++k)
        tstore(qp + k, __float_as_uint(qS[bl][i0 + k]), (unsigned)(t + 1));
    }
    zgemv64(tid, decW4, hl16, part);   // shadow: hides q exchange flight
    __syncthreads();

    // ==== Phase B: poll q full; energies for own 4-s slice; publish scores ====
    {
      int b_l = tid >> 6, c = tid & 63;
      const u64b* p = qg64 + (size_t)(g * 4 + b_l) * 512 + c * 8;
      u64b v0, v1, v2, v3, v4, v5, v6, v7;
      poll8(p, (unsigned)(t + 1), v0, v1, v2, v3, v4, v5, v6, v7);
      int lw0 = c * 2, lw1 = c * 2 + 1;
      float4 q0 = {__uint_as_float((unsigned)v0), __uint_as_float((unsigned)v1),
                   __uint_as_float((unsigned)v2), __uint_as_float((unsigned)v3)};
      float4 q1 = {__uint_as_float((unsigned)v4), __uint_as_float((unsigned)v5),
                   __uint_as_float((unsigned)v6), __uint_as_float((unsigned)v7)};
      qf4[b_l * 128 + (lw0 ^ ((lw0 >> 3) & 7))] = q0;
      qf4[b_l * 128 + (lw1 ^ ((lw1 >> 3) & 7))] = q1;
    }
    __syncthreads();
    {
      int p = tid >> 4, lane16 = tid & 15;
      int b_l = p >> 2, s_l = p & 3;
      int s = gb * 4 + s_l;
      const uint4* ep = (const uint4*)(eprojb + ((size_t)(b0 + b_l) * SSRC + s) * H_) + lane16 * 4;
      uint4 e0 = ep[0], e1 = ep[1], e2 = ep[2], e3 = ep[3];
      unsigned ev[8] = {e0.x, e0.y, e0.z, e0.w, e1.x, e1.y, e1.z, e1.w};
      unsigned ev2[8] = {e2.x, e2.y, e2.z, e2.w, e3.x, e3.y, e3.z, e3.w};
      float acc = 0.f;
#pragma unroll
      for (int i = 0; i < 8; ++i) {
        int lr = lane16 * 8 + i;
        float4 q = qf4[b_l * 128 + (lr ^ ((lr >> 3) & 7))];
        float4 vv = vf4[lr ^ ((lr >> 3) & 7)];
        unsigned lo = (i < 4) ? ev[i * 2] : ev2[(i - 4) * 2];
        unsigned hi = (i < 4) ? ev[i * 2 + 1] : ev2[(i - 4) * 2 + 1];
        acc += vv.x * tanh_(b2f((u16)(lo & 0xffff)) + q.x);
        acc += vv.y * tanh_(b2f((u16)(lo >> 16)) + q.y);
        acc += vv.z * tanh_(b2f((u16)(hi & 0xffff)) + q.z);
        acc += vv.w * tanh_(b2f((u16)(hi >> 16)) + q.w);
      }
      acc += __shfl_xor(acc, 1);
      acc += __shfl_xor(acc, 2);
      acc += __shfl_xor(acc, 4);
      acc += __shfl_xor(acc, 8);
      if (lane16 == 0) scr16[b_l][s_l] = acc;
    }
    __syncthreads();
    if (tid < 4) {
      u64b* sp = scoreb64 + (size_t)(g * 4 + tid) * 128 + gb * 4;
#pragma unroll
      for (int k = 0; k < 4; ++k)
        tstore(sp + k, __float_as_uint(scr16[tid][k]), (unsigned)(t + 1));
    }

    // ==== Phase C: poll scores; softmax; eoP partials; z combine; gates; publish h ====
    if (tid < 128) {
      int row = tid >> 5, c4 = tid & 31;
      const u64b* p = scoreb64 + (size_t)(g * 4 + row) * 128 + c4 * 4;
      u64b v0, v1, v2, v3;
      poll4(p, (unsigned)(t + 1), v0, v1, v2, v3);
      scoreS[row][c4 * 4 + 0] = __uint_as_float((unsigned)v0);
      scoreS[row][c4 * 4 + 1] = __uint_as_float((unsigned)v1);
      scoreS[row][c4 * 4 + 2] = __uint_as_float((unsigned)v2);
      scoreS[row][c4 * 4 + 3] = __uint_as_float((unsigned)v3);
    }
    __syncthreads();
    {
      int w = tid >> 6, lane = tid & 63;
      float s1 = scoreS[w][lane], s2v = scoreS[w][64 + lane];
      float m = fmaxf(s1, s2v);
#pragma unroll
      for (int off = 32; off; off >>= 1) m = fmaxf(m, __shfl_xor(m, off));
      float e1 = __expf(s1 - m), e2 = __expf(s2v - m);
      float sm = e1 + e2;
#pragma unroll
      for (int off = 32; off; off >>= 1) sm += __shfl_xor(sm, off);
      float inv = 1.0f / sm;
      aS[w][lane] = e1 * inv;
      aS[w][64 + lane] = e2 * inv;
    }
    __syncthreads();
    {
      int sq = tid >> 5, cp = tid & 31;
      const unsigned* eoPu = (const unsigned*)eoPb;
      float a0 = 0.f, a1 = 0.f, a2 = 0.f, a3 = 0.f, a4 = 0.f, a5 = 0.f, a6 = 0.f, a7 = 0.f;
#pragma unroll 4
      for (int s = sq * 16; s < sq * 16 + 16; ++s) {
        unsigned u0 = eoPu[((size_t)(b0 + 0) * SSRC + s) * 1024 + gb * 32 + cp];
        unsigned u1 = eoPu[((size_t)(b0 + 1) * SSRC + s) * 1024 + gb * 32 + cp];
        unsigned u2 = eoPu[((size_t)(b0 + 2) * SSRC + s) * 1024 + gb * 32 + cp];
        unsigned u3 = eoPu[((size_t)(b0 + 3) * SSRC + s) * 1024 + gb * 32 + cp];
        float w0 = aS[0][s], w1 = aS[1][s], w2 = aS[2][s], w3 = aS[3][s];
        a0 += w0 * b2f((u16)(u0 & 0xffff)); a1 += w0 * b2f((u16)(u0 >> 16));
        a2 += w1 * b2f((u16)(u1 & 0xffff)); a3 += w1 * b2f((u16)(u1 >> 16));
        a4 += w2 * b2f((u16)(u2 & 0xffff)); a5 += w2 * b2f((u16)(u2 >> 16));
        a6 += w3 * b2f((u16)(u3 & 0xffff)); a7 += w3 * b2f((u16)(u3 >> 16));
      }
      float4 lo = {a0, a2, a4, a6}, hi = {a1, a3, a5, a7};
      *(float4*)&partE[sq][cp * 2][0] = lo;
      *(float4*)&partE[sq][cp * 2 + 1][0] = hi;
    }
    __syncthreads();
    {
      int b_l = tid >> 6, rl = tid & 63;
      float z = 0.f;
#pragma unroll
      for (int kq = 0; kq < 16; ++kq) z += part[kq][rl ^ (kq & 7)][b_l];
#pragma unroll
      for (int sq2 = 0; sq2 < 8; ++sq2) z += partE[sq2][rl][b_l];
      int grow = (rl >> 4) * 512 + ds0 + (rl & 15);
      z += b2f(decXW[((size_t)(b0 + b_l) * STGT + t) * G4 + grow]);
      zx[b_l][rl] = z;
    }
    __syncthreads();
    if (tid < 64) {
      int bl = tid >> 4, jl = tid & 15;
      float iv = zx[bl][jl], fv = zx[bl][16 + jl], gv = zx[bl][32 + jl], ov = zx[bl][48 + jl];
      float cn = sigm(fv) * cS[bl][jl] + sigm(iv) * tanh_(gv);
      float hn = sigm(ov) * tanh_(cn);
      cS[bl][jl] = cn;
      dech[((size_t)(b0 + bl) * STGT + t) * H_ + ds0 + jl] = f2b(hn);
      float hn1 = __shfl_down(hn, 1);
      if ((jl & 1) == 0)
        tstore(hd64 + (size_t)(b0 + bl) * 256 + gb * 8 + (jl >> 1), pk2(hn, hn1),
               (unsigned)(t + 2));
    }
    __syncthreads();
  }
}

// ---------------- workspace layout (bytes) ----------------
#define OFF_HBE    0u           // u64 [2][32][256] = 128 KB (tagged, memset 0)
#define OFF_HD     131072u      // u64 [32][256] = 64 KB
#define OFF_QG     196608u      // u64 [8][4][512] = 128 KB
#define OFF_SC     327680u      // u64 [8][4][128] = 32 KB -> tagged region ends 360448
#define OFF_CFIN   360448u      // f32 [32][512] = 64 KB
#define OFF_AENC   524288u      // 2 MB
#define OFF_ADEC   2621440u     // 1 MB
#define OFF_WIHE   3670016u     // 1 MB
#define OFF_WIHD   4718592u     // 1 MB
#define OFF_WEB    5767168u     // 512 KB
#define OFF_WIHCP  6291456u     // 2 MB
#define OFF_OUTW   8388608u     // 32.77 MB
#define OFF_ENCXW  41943040u    // 16.78 MB  [aliased by eoP after encoder]
#define OFF_DECXW  58720256u    // 8.39 MB
#define OFF_EPROJ  67108864u    // 4.19 MB
#define OFF_EO     71303168u    // 4.19 MB
#define OFF_DECH   75497472u    // 2.10 MB -> end 77.6 MB

extern "C" void kernel_launch(void* const* d_in, const int* in_sizes, int n_in,
                              void* d_out, int out_size, void* d_ws, size_t ws_size,
                              hipStream_t stream)
{
  const int*   src     = (const int*)d_in[0];
  const int*   tgt     = (const int*)d_in[1];
  const float* enc_emb = (const float*)d_in[2];
  const float* enc_Wih = (const float*)d_in[3];
  const float* enc_Whh = (const float*)d_in[4];
  const float* enc_b   = (const float*)d_in[5];
  const float* attn_W  = (const float*)d_in[6];
  const float* attn_b  = (const float*)d_in[7];
  const float* attn_v  = (const float*)d_in[8];
  const float* dec_emb = (const float*)d_in[9];
  const float* dec_Wih = (const float*)d_in[10];
  const float* dec_Whh = (const float*)d_in[11];
  const float* dec_b   = (const float*)d_in[12];
  const float* out_W   = (const float*)d_in[13];
  const float* out_b   = (const float*)d_in[14];

  char* ws = (char*)d_ws;
  u64b*  hbufE  = (u64b*)(ws + OFF_HBE);
  u64b*  hd64   = (u64b*)(ws + OFF_HD);
  u64b*  qg64   = (u64b*)(ws + OFF_QG);
  u64b*  scb64  = (u64b*)(ws + OFF_SC);
  float* cfin   = (float*)(ws + OFF_CFIN);
  u16*   A_enc  = (u16*)(ws + OFF_AENC);
  u16*   A_dec  = (u16*)(ws + OFF_ADEC);
  u16*   WihE   = (u16*)(ws + OFF_WIHE);
  u16*   WihD   = (u16*)(ws + OFF_WIHD);
  u16*   Web    = (u16*)(ws + OFF_WEB);
  u16*   WihCp  = (u16*)(ws + OFF_WIHCP);
  u16*   outWb  = (u16*)(ws + OFF_OUTW);
  u16*   encXW  = (u16*)(ws + OFF_ENCXW);
  u16*   eoPb   = (u16*)(ws + OFF_ENCXW);   // alias: encXW dead after encoder
  u16*   decXW  = (u16*)(ws + OFF_DECXW);
  u16*   eprojb = (u16*)(ws + OFF_EPROJ);
  u16*   eo_g   = (u16*)(ws + OFF_EO);
  u16*   dech   = (u16*)(ws + OFF_DECH);

  // zero all tagged exchange buffers (tag 0 = "empty"/initial h=0)
  (void)hipMemsetAsync(d_ws, 0, 360448, stream);

  prep_kernel<<<2048, 256, 0, stream>>>(src, tgt, enc_emb, dec_emb, enc_Wih, dec_Wih,
                                        attn_W, out_W, A_enc, A_dec, WihE, WihD, Web, WihCp, outWb);

  // encXW = emb_src @ enc_Wih^T + enc_b   (4096 x 2048 x 256) -> bf16
  gemm_nt<256, true><<<512, 256, 0, stream>>>(A_enc, WihE, enc_b, (void*)encXW, 4096, 2048);
  // decXW = emb_tgt @ dec_Wih[:, :E]^T + dec_b  (2048 x 2048 x 256) -> bf16
  gemm_nt<256, true><<<256, 256, 0, stream>>>(A_dec, WihD, dec_b, (void*)decXW, 2048, 2048);

  encoder_kernel<<<256, 256, 0, stream>>>(enc_Whh, encXW, hbufE, hd64, cfin, eo_g);

  // eproj = enc_out @ W_e^T  (4096 x 512 x 512) -> bf16
  gemm_nt<512, true><<<128, 256, 0, stream>>>(eo_g, Web, nullptr, (void*)eprojb, 4096, 512);
  // eoP = enc_out @ WihCp^T  (4096 x 2048 x 512) -> bf16  (overwrites encXW)
  gemm_nt<512, true><<<512, 256, 0, stream>>>(eo_g, WihCp, nullptr, (void*)eoPb, 4096, 2048);

  decoder_kernel<<<256, 256, 0, stream>>>(dec_Whh, attn_W, attn_b, attn_v,
                                          eprojb, decXW, eoPb, hd64, cfin,
                                          qg64, scb64, dech);

  // out = dec_h @ out_W^T + out_b  (2048 x 32000 x 512) -> f32
  gemm_nt<512, false><<<4000, 256, 0, stream>>>(dech, outWb, out_b, d_out, 2048, 32000);
}

// Round 11
// 1388.064 us; speedup vs baseline: 1.2497x; 1.1921x over previous
//
#include <hip/hip_runtime.h>

#define B_    32
#define SSRC  128
#define STGT  64
#define E_    256
#define H_    512
#define G4    2048
#define V_    32000

typedef unsigned short u16;
typedef short bf16x8 __attribute__((ext_vector_type(8)));
typedef float f32x4 __attribute__((ext_vector_type(4)));

__device__ __forceinline__ u16 f2b(float f) {
  unsigned u = __float_as_uint(f);
  u += 0x7FFFu + ((u >> 16) & 1u);
  return (u16)(u >> 16);
}
__device__ __forceinline__ float b2f(u16 h) {
  return __uint_as_float(((unsigned)h) << 16);
}
__device__ __forceinline__ unsigned pk2(float lo, float hi) {
  return (unsigned)f2b(lo) | (((unsigned)f2b(hi)) << 16);
}
__device__ __forceinline__ float sigm(float x) { return 1.0f / (1.0f + __expf(-x)); }
__device__ __forceinline__ float tanh_(float x) { return 1.0f - 2.0f / (1.0f + __expf(2.0f * x)); }

#if defined(__has_builtin)
#if __has_builtin(__builtin_amdgcn_fdot2_f32_bf16)
#define HAS_DOT2 1
#endif
#endif
#ifdef HAS_DOT2
typedef __bf16 b162 __attribute__((ext_vector_type(2)));
__device__ __forceinline__ float dot2u(unsigned a, unsigned b, float acc) {
  return __builtin_amdgcn_fdot2_f32_bf16(__builtin_bit_cast(b162, a),
                                         __builtin_bit_cast(b162, b), acc, false);
}
#else
__device__ __forceinline__ float dot2u(unsigned a, unsigned b, float acc) {
  acc += __uint_as_float(a << 16) * __uint_as_float(b << 16);
  acc += __uint_as_float(a & 0xffff0000u) * __uint_as_float(b & 0xffff0000u);
  return acc;
}
#endif
__device__ __forceinline__ float dot4(uint4 w, uint4 h, float acc) {
  return dot2u(w.w, h.w, dot2u(w.z, h.z, dot2u(w.y, h.y, dot2u(w.x, h.x, acc))));
}

__device__ __forceinline__ int swz64(int c) {
  return (c & ~3) | ((c & 3) ^ ((c >> 3) & 3));
}

// ---- device-coherent accesses ----
__device__ __forceinline__ uint4 cload4(const void* p) {
  uint4 r;
  asm volatile("global_load_dwordx4 %0, %1, off sc0 sc1\n\ts_waitcnt vmcnt(0)"
               : "=&v"(r) : "v"(p) : "memory");
  return r;
}
__device__ __forceinline__ void cstoref(float* p, float v) {
  asm volatile("global_store_dword %0, %1, off sc0 sc1" :: "v"(p), "v"(v) : "memory");
}
__device__ __forceinline__ void cstoreu(unsigned* p, unsigned v) {
  asm volatile("global_store_dword %0, %1, off sc0 sc1" :: "v"(p), "v"(v) : "memory");
}
__device__ __forceinline__ float cloadf_relaxed(const float* p) {
  return __hip_atomic_load(p, __ATOMIC_RELAXED, __HIP_MEMORY_SCOPE_AGENT);
}

// ---- split barrier: arrive (drain stores + flag) ... optional shadow ... wait ----
__device__ __forceinline__ void arrive(int* flags, int myid, int target) {
  asm volatile("s_waitcnt vmcnt(0)" ::: "memory");
  __syncthreads();
  if (threadIdx.x == 0)
    __hip_atomic_store(flags + myid, target, __ATOMIC_RELAXED, __HIP_MEMORY_SCOPE_AGENT);
}
__device__ __forceinline__ void waitbar(int* flags, int target) {
  if (threadIdx.x < 64) {
    int l = threadIdx.x & 31;
    while (__hip_atomic_load(flags + l, __ATOMIC_RELAXED, __HIP_MEMORY_SCOPE_AGENT) < target)
      __builtin_amdgcn_s_sleep(1);
  }
  __syncthreads();
  asm volatile("" ::: "memory");
}
__device__ __forceinline__ void gbar(int* flags, int myid, int target) {
  arrive(flags, myid, target);
  waitbar(flags, target);
}

// ---------------- prep: gathers + bf16 conversions ----------------
__global__ void prep_kernel(const int* __restrict__ src, const int* __restrict__ tgt,
                            const float* __restrict__ enc_emb, const float* __restrict__ dec_emb,
                            const float* __restrict__ enc_Wih, const float* __restrict__ dec_Wih,
                            const float* __restrict__ attn_W, const float* __restrict__ out_W,
                            u16* __restrict__ A_enc, u16* __restrict__ A_dec,
                            u16* __restrict__ WihE, u16* __restrict__ WihD,
                            u16* __restrict__ Web, u16* __restrict__ WihCp,
                            u16* __restrict__ outWb)
{
  const long n_outw = (long)V_ * H_;
  const long n_aenc = (long)B_ * SSRC * E_;
  const long n_adec = (long)B_ * STGT * E_;
  const long n_wih  = (long)G4 * E_;
  const long n_web  = (long)H_ * H_;
  const long n_wcp  = (long)G4 * H_;
  const long total = n_outw + n_aenc + n_adec + 2 * n_wih + n_web + n_wcp;
  for (long i = (long)blockIdx.x * blockDim.x + threadIdx.x; i < total;
       i += (long)gridDim.x * blockDim.x) {
    long x = i;
    if (x < n_outw) { outWb[x] = f2b(out_W[x]); continue; }
    x -= n_outw;
    if (x < n_aenc) {
      int row = (int)(x >> 8), e = (int)(x & 255);
      A_enc[x] = f2b(enc_emb[(size_t)src[row] * E_ + e]);
      continue;
    }
    x -= n_aenc;
    if (x < n_adec) {
      int row = (int)(x >> 8), e = (int)(x & 255);
      A_dec[x] = f2b(dec_emb[(size_t)tgt[row] * E_ + e]);
      continue;
    }
    x -= n_adec;
    if (x < n_wih) { WihE[x] = f2b(enc_Wih[x]); continue; }
    x -= n_wih;
    if (x < n_wih) {
      int r = (int)(x >> 8), e = (int)(x & 255);
      WihD[x] = f2b(dec_Wih[(size_t)r * 768 + e]);
      continue;
    }
    x -= n_wih;
    if (x < n_web) {
      int d = (int)(x >> 9), k = (int)(x & 511);
      Web[x] = f2b(attn_W[(size_t)d * 1024 + 512 + k]);
      continue;
    }
    x -= n_web;
    {
      // permuted WihC rows: n = gb*64 + gate*16 + jl  ->  orig gate*512 + gb*16 + jl
      int n = (int)(x >> 9), k = (int)(x & 511);
      int gb = n >> 6, gate = (n >> 4) & 3, jl = n & 15;
      int orig = gate * 512 + gb * 16 + jl;
      WihCp[x] = f2b(dec_Wih[(size_t)orig * 768 + 256 + k]);
    }
  }
}

// ---------------- NT GEMM: C[m][n] = sum_k A[m][k]*B[n][k] + bias[n] ----------------
template<int KTOT, bool OBF>
__global__ __launch_bounds__(256, 2) void gemm_nt(
    const u16* __restrict__ A, const u16* __restrict__ Bm,
    const float* __restrict__ bias, void* __restrict__ Cv, int M, int N)
{
  int nbm = M >> 7;
  int bn = blockIdx.x / nbm;
  int bm = blockIdx.x % nbm;
  int w = threadIdx.x >> 6, l = threadIdx.x & 63;
  int wr = w >> 1, wc = w & 1;
  int m0 = bm * 128 + wr * 64, n0 = bn * 128 + wc * 64;
  int lr = l & 15, ko = (l >> 4) * 8;
  f32x4 acc[4][4] = {};
  const u16* Ap = A + (size_t)(m0 + lr) * KTOT + ko;
  const u16* Bp = Bm + (size_t)(n0 + lr) * KTOT + ko;
  for (int k0 = 0; k0 < KTOT; k0 += 32) {
    bf16x8 af[4], bfr[4];
#pragma unroll
    for (int i = 0; i < 4; ++i) af[i] = *(const bf16x8*)(Ap + (size_t)i * 16 * KTOT + k0);
#pragma unroll
    for (int i = 0; i < 4; ++i) bfr[i] = *(const bf16x8*)(Bp + (size_t)i * 16 * KTOT + k0);
#pragma unroll
    for (int i = 0; i < 4; ++i)
#pragma unroll
      for (int j = 0; j < 4; ++j)
        acc[i][j] = __builtin_amdgcn_mfma_f32_16x16x32_bf16(af[i], bfr[j], acc[i][j], 0, 0, 0);
  }
  int rbase = (l >> 4) * 4;
#pragma unroll
  for (int i = 0; i < 4; ++i) {
#pragma unroll
    for (int j = 0; j < 4; ++j) {
      int gn = n0 + j * 16 + lr;
      float bv = bias ? bias[gn] : 0.f;
#pragma unroll
      for (int r = 0; r < 4; ++r) {
        int gm = m0 + i * 16 + rbase + r;
        float v = acc[i][j][r] + bv;
        if (OBF) ((u16*)Cv)[(size_t)gm * N + gn] = f2b(v);
        else     ((float*)Cv)[(size_t)gm * N + gn] = v;
      }
    }
  }
}

// ---- shared z-GEMV: 64 gate-rows x 512 k, bf16, swizzled LDS ----
__device__ __forceinline__ void zgemv64(int tid, const uint4* Wu, const uint4* Hu,
                                        float (*part)[64][4]) {
  int rq = tid >> 4, kq = tid & 15;
  float acc[4][4] = {};
#pragma unroll
  for (int u = 0; u < 4; ++u) {
    int sc = swz64(kq * 4 + u);
    uint4 h0 = Hu[sc], h1 = Hu[64 + sc], h2 = Hu[128 + sc], h3 = Hu[192 + sc];
#pragma unroll
    for (int r = 0; r < 4; ++r) {
      uint4 wv = Wu[(rq * 4 + r) * 64 + sc];
      acc[r][0] = dot4(wv, h0, acc[r][0]);
      acc[r][1] = dot4(wv, h1, acc[r][1]);
      acc[r][2] = dot4(wv, h2, acc[r][2]);
      acc[r][3] = dot4(wv, h3, acc[r][3]);
    }
  }
#pragma unroll
  for (int r = 0; r < 4; ++r) {
    float4 v = {acc[r][0], acc[r][1], acc[r][2], acc[r][3]};
    *(float4*)&part[kq][(rq * 4 + r) ^ (kq & 7)][0] = v;
  }
}

template<typename GrowF>
__device__ __forceinline__ void fillw64(int tid, const float* Wsrc, uint4* Wu, GrowF grow) {
#pragma unroll 4
  for (int i = 0; i < 16; ++i) {
    int idx4 = tid + i * 256;
    int row = idx4 >> 6, c = idx4 & 63;
    const float* s = Wsrc + (size_t)grow(row) * 512 + c * 8;
    float4 a = *(const float4*)s, b4 = *(const float4*)(s + 4);
    uint4 pkv = {pk2(a.x, a.y), pk2(a.z, a.w), pk2(b4.x, b4.y), pk2(b4.z, b4.w)};
    Wu[row * 64 + swz64(c)] = pkv;
  }
}

// ---------------- encoder: persistent, 8 groups x 32 blocks, 1 barrier/step --------
__global__ __launch_bounds__(256, 1) void encoder_kernel(
    const float* __restrict__ enc_Whh, const u16* __restrict__ encXW,
    unsigned* __restrict__ h16buf /* u32 [2][32][256] */,
    float* __restrict__ cfin, u16* __restrict__ eo_g, int* __restrict__ bars)
{
  const int tid = threadIdx.x;
  const int g = blockIdx.x & 7;
  const int gb = blockIdx.x >> 3;
  const int b0 = g * 4;
  const int ds0 = gb * 16;
  int* flags = bars + g * 64;

  __shared__ uint4 encW4[64 * 64];   // 64 KB
  __shared__ uint4 hl16[4 * 64];     // 4 KB
  __shared__ float part[16][64][4];  // 16 KB
  __shared__ float zx[4][64];
  __shared__ float cS[4][16];

  if (tid < 64) cS[tid >> 4][tid & 15] = 0.f;
  fillw64(tid, enc_Whh, encW4, [&](int row) { return (row >> 4) * 512 + ds0 + (row & 15); });
  __syncthreads();

  const int bl_c = tid >> 6, rl_c = tid & 63;
  const int grow_c = (rl_c >> 4) * 512 + ds0 + (rl_c & 15);
  const u16* xwp = encXW + (size_t)(b0 + bl_c) * SSRC * G4 + grow_c;

  for (int t = 0; t < SSRC; ++t) {
    u16 xw = xwp[(size_t)t * G4];  // prefetch: independent of h, overlaps h stage
    // stage h (coherent, 1 dwordx4/thread)
    {
      int row = tid >> 6, c = tid & 63;
      uint4 v = cload4((const uint4*)h16buf + (size_t)(t & 1) * 2048 + (b0 + row) * 64 + c);
      hl16[row * 64 + swz64(c)] = v;
    }
    __syncthreads();
    zgemv64(tid, encW4, hl16, part);
    __syncthreads();
    {
      float z = 0.f;
#pragma unroll
      for (int kq = 0; kq < 16; ++kq) z += part[kq][rl_c ^ (kq & 7)][bl_c];
      z += b2f(xw);
      zx[bl_c][rl_c] = z;
    }
    __syncthreads();
    if (tid < 64) {
      int bl = tid >> 4, jl = tid & 15;
      float iv = zx[bl][jl], fv = zx[bl][16 + jl], gv = zx[bl][32 + jl], ov = zx[bl][48 + jl];
      float cn = sigm(fv) * cS[bl][jl] + sigm(iv) * tanh_(gv);
      float hn = sigm(ov) * tanh_(cn);
      cS[bl][jl] = cn;
      eo_g[((size_t)(b0 + bl) * SSRC + t) * H_ + ds0 + jl] = f2b(hn);
      float hn1 = __shfl_down(hn, 1);
      if ((jl & 1) == 0)
        cstoreu(h16buf + (size_t)((t + 1) & 1) * 8192 + (size_t)(b0 + bl) * 256 + gb * 8 + (jl >> 1),
                pk2(hn, hn1));
    }
    gbar(flags, gb, t + 1);
  }
  if (tid < 64)
    cfin[(size_t)(b0 + (tid >> 4)) * H_ + ds0 + (tid & 15)] = cS[tid >> 4][tid & 15];
}

// ---------------- decoder: persistent, 2 barriers/step ----------------------------
__global__ __launch_bounds__(256, 1) void decoder_kernel(
    const float* __restrict__ dec_Whh, const float* __restrict__ attn_W,
    const float* __restrict__ attn_b, const float* __restrict__ attn_v,
    const u16* __restrict__ eprojb, const u16* __restrict__ decXW,
    const u16* __restrict__ eoPb,
    unsigned* __restrict__ hd16, const float* __restrict__ cfin,
    float* __restrict__ vpart /* f32 [8*32][512] */,
    u16* __restrict__ dech, int* __restrict__ bars)
{
  const int tid = threadIdx.x;
  const int g = blockIdx.x & 7;
  const int gb = blockIdx.x >> 3;
  const int b0 = g * 4;
  const int ds0 = gb * 16;
  int* flags = bars + g * 64;
  int ep_ = 0;

  __shared__ uint4 decW4[64 * 64];   // 64 KB
  __shared__ uint4 Whb4[16 * 64];    // 16 KB
  __shared__ uint4 epL[512][2];      // 16 KB (step-invariant eproj slice)
  __shared__ uint4 hl16[4 * 64];     // 4 KB
  __shared__ float part[16][64][4];  // 16 KB
  __shared__ float partE[8][64][4];  // 8 KB
  __shared__ float scoreS[4][128];   // 2 KB
  __shared__ float aS[4][128];       // 2 KB
  __shared__ float zx[4][64];
  __shared__ float qS[4][16];
  __shared__ float cS[4][16];
  __shared__ float vS[16], bS[16];

  if (tid < 64) cS[tid >> 4][tid & 15] = cfin[(size_t)(b0 + (tid >> 4)) * H_ + ds0 + (tid & 15)];
  if (tid < 16) { vS[tid] = attn_v[ds0 + tid]; bS[tid] = attn_b[ds0 + tid]; }
  fillw64(tid, dec_Whh, decW4, [&](int row) { return (row >> 4) * 512 + ds0 + (row & 15); });
#pragma unroll
  for (int i = 0; i < 4; ++i) {
    int idx4 = tid + i * 256;
    int row = idx4 >> 6, c = idx4 & 63;
    const float* s = attn_W + (size_t)(ds0 + row) * 1024 + c * 8;
    float4 a = *(const float4*)s, b4 = *(const float4*)(s + 4);
    uint4 pkv = {pk2(a.x, a.y), pk2(a.z, a.w), pk2(b4.x, b4.y), pk2(b4.z, b4.w)};
    Whb4[row * 64 + (c ^ (row & 7))] = pkv;
  }
  // eproj slice -> LDS once (step-invariant)
#pragma unroll
  for (int r = 0; r < 2; ++r) {
    int idx = tid + r * 256;
    int b_l = idx >> 7, s = idx & 127;
    const uint4* ep = (const uint4*)(eprojb + (((size_t)(b0 + b_l) * SSRC + s) << 9) + ds0);
    epL[idx][0] = ep[0];
    epL[idx][1] = ep[1];
  }
  // ---- preload this block's static eoP slice into registers (64 KB/block) ----
  // eoPb columns are PERMUTED (WihCp): column gb*64 + gate*16 + jl <-> orig gate*512+gb*16+jl.
  // This block's slice is the contiguous u32 range [gb*32, gb*32+32) of each row. (r7 pairing)
  const int sq = tid >> 5, cp = tid & 31;
  const int n32 = gb * 32 + cp;
  uint4 eor[16];
  {
    const unsigned* eoPu = (const unsigned*)eoPb;
#pragma unroll
    for (int si = 0; si < 16; ++si) {
      int s = sq * 16 + si;
      eor[si].x = eoPu[((size_t)(b0 + 0) * SSRC + s) * 1024 + n32];
      eor[si].y = eoPu[((size_t)(b0 + 1) * SSRC + s) * 1024 + n32];
      eor[si].z = eoPu[((size_t)(b0 + 2) * SSRC + s) * 1024 + n32];
      eor[si].w = eoPu[((size_t)(b0 + 3) * SSRC + s) * 1024 + n32];
    }
  }
  __syncthreads();

  const int bl_c = tid >> 6, rl_c = tid & 63;
  const int grow_c = (rl_c >> 4) * 512 + ds0 + (rl_c & 15);
  const u16* xwp = decXW + (size_t)(b0 + bl_c) * STGT * G4 + grow_c;

  for (int t = 0; t < STGT; ++t) {
    u16 xw = xwp[(size_t)t * G4];  // prefetch bias row (independent of h)
    // ==== Phase 1: stage h; local q-slice; energy d-partials; publish; shadow=zgemv ====
    {
      int row = tid >> 6, c = tid & 63;
      uint4 v = cload4((const uint4*)hd16 + (b0 + row) * 64 + c);
      hl16[row * 64 + swz64(c)] = v;
    }
    __syncthreads();
    {
      int b_l = tid >> 6, d_l = (tid >> 2) & 15, kq4 = tid & 3;
      float acc = 0.f;
#pragma unroll
      for (int u = 0; u < 16; ++u) {
        int c = kq4 * 16 + u;
        acc = dot4(Whb4[d_l * 64 + (c ^ (d_l & 7))], hl16[b_l * 64 + swz64(c)], acc);
      }
      acc += __shfl_xor(acc, 1);
      acc += __shfl_xor(acc, 2);
      if (kq4 == 0) qS[b_l][d_l] = acc + bS[d_l];
    }
    __syncthreads();
    {
      float* vp = vpart + ((size_t)g * 32 + gb) * 512;
#pragma unroll
      for (int r = 0; r < 2; ++r) {
        int idx = tid + r * 256;
        int b_l = idx >> 7;
        uint4 e0 = epL[idx][0], e1 = epL[idx][1];
        float acc = 0.f;
        acc += vS[0]  * tanh_(b2f((u16)(e0.x & 0xffff)) + qS[b_l][0]);
        acc += vS[1]  * tanh_(b2f((u16)(e0.x >> 16))    + qS[b_l][1]);
        acc += vS[2]  * tanh_(b2f((u16)(e0.y & 0xffff)) + qS[b_l][2]);
        acc += vS[3]  * tanh_(b2f((u16)(e0.y >> 16))    + qS[b_l][3]);
        acc += vS[4]  * tanh_(b2f((u16)(e0.z & 0xffff)) + qS[b_l][4]);
        acc += vS[5]  * tanh_(b2f((u16)(e0.z >> 16))    + qS[b_l][5]);
        acc += vS[6]  * tanh_(b2f((u16)(e0.w & 0xffff)) + qS[b_l][6]);
        acc += vS[7]  * tanh_(b2f((u16)(e0.w >> 16))    + qS[b_l][7]);
        acc += vS[8]  * tanh_(b2f((u16)(e1.x & 0xffff)) + qS[b_l][8]);
        acc += vS[9]  * tanh_(b2f((u16)(e1.x >> 16))    + qS[b_l][9]);
        acc += vS[10] * tanh_(b2f((u16)(e1.y & 0xffff)) + qS[b_l][10]);
        acc += vS[11] * tanh_(b2f((u16)(e1.y >> 16))    + qS[b_l][11]);
        acc += vS[12] * tanh_(b2f((u16)(e1.z & 0xffff)) + qS[b_l][12]);
        acc += vS[13] * tanh_(b2f((u16)(e1.z >> 16))    + qS[b_l][13]);
        acc += vS[14] * tanh_(b2f((u16)(e1.w & 0xffff)) + qS[b_l][14]);
        acc += vS[15] * tanh_(b2f((u16)(e1.w >> 16))    + qS[b_l][15]);
        cstoref(vp + idx, acc);
      }
    }
    arrive(flags, gb, ++ep_);
    zgemv64(tid, decW4, hl16, part);   // shadow: hides vpart exchange flight
    waitbar(flags, ep_);

    // ==== Phase 2: gather partials -> scores; softmax; eoP-reg z; gates ====
    {
      int b_l = tid >> 6, s0 = (tid & 63) * 2;
      float a0 = 0.f, a1 = 0.f;
#pragma unroll 8
      for (int j = 0; j < 32; ++j) {
        const float* p = vpart + ((size_t)g * 32 + j) * 512 + b_l * 128 + s0;
        a0 += cloadf_relaxed(p);
        a1 += cloadf_relaxed(p + 1);
      }
      scoreS[b_l][s0] = a0;
      scoreS[b_l][s0 + 1] = a1;
    }
    __syncthreads();
    {
      int w = tid >> 6, lane = tid & 63;
      float s1 = scoreS[w][lane], s2v = scoreS[w][64 + lane];
      float m = fmaxf(s1, s2v);
#pragma unroll
      for (int off = 32; off; off >>= 1) m = fmaxf(m, __shfl_xor(m, off));
      float e1 = __expf(s1 - m), e2 = __expf(s2v - m);
      float sm = e1 + e2;
#pragma unroll
      for (int off = 32; off; off >>= 1) sm += __shfl_xor(sm, off);
      float inv = 1.0f / sm;
      aS[w][lane] = e1 * inv;
      aS[w][64 + lane] = e2 * inv;
    }
    __syncthreads();
    {
      float a0 = 0.f, a1 = 0.f, a2 = 0.f, a3 = 0.f, a4 = 0.f, a5 = 0.f, a6 = 0.f, a7 = 0.f;
#pragma unroll
      for (int si = 0; si < 16; ++si) {
        int s = sq * 16 + si;
        float w0 = aS[0][s], w1 = aS[1][s], w2 = aS[2][s], w3 = aS[3][s];
        unsigned u0 = eor[si].x, u1 = eor[si].y, u2 = eor[si].z, u3 = eor[si].w;
        a0 += w0 * b2f((u16)(u0 & 0xffff)); a1 += w0 * b2f((u16)(u0 >> 16));
        a2 += w1 * b2f((u16)(u1 & 0xffff)); a3 += w1 * b2f((u16)(u1 >> 16));
        a4 += w2 * b2f((u16)(u2 & 0xffff)); a5 += w2 * b2f((u16)(u2 >> 16));
        a6 += w3 * b2f((u16)(u3 & 0xffff)); a7 += w3 * b2f((u16)(u3 >> 16));
      }
      // permuted layout: local row = cp*2 (+1)  (r7 pairing)
      int r0 = cp * 2;
      float4 lo = {a0, a2, a4, a6}, hi = {a1, a3, a5, a7};
      *(float4*)&partE[sq][r0][0] = lo;
      *(float4*)&partE[sq][r0 + 1][0] = hi;
    }
    __syncthreads();
    {
      float z = 0.f;
#pragma unroll
      for (int kq = 0; kq < 16; ++kq) z += part[kq][rl_c ^ (kq & 7)][bl_c];
#pragma unroll
      for (int sq2 = 0; sq2 < 8; ++sq2) z += partE[sq2][rl_c][bl_c];
      z += b2f(xw);
      zx[bl_c][rl_c] = z;
    }
    __syncthreads();
    if (tid < 64) {
      int bl = tid >> 4, jl = tid & 15;
      float iv = zx[bl][jl], fv = zx[bl][16 + jl], gv = zx[bl][32 + jl], ov = zx[bl][48 + jl];
      float cn = sigm(fv) * cS[bl][jl] + sigm(iv) * tanh_(gv);
      float hn = sigm(ov) * tanh_(cn);
      cS[bl][jl] = cn;
      dech[((size_t)(b0 + bl) * STGT + t) * H_ + ds0 + jl] = f2b(hn);
      float hn1 = __shfl_down(hn, 1);
      if ((jl & 1) == 0)
        cstoreu(hd16 + (size_t)(b0 + bl) * 256 + gb * 8 + (jl >> 1), pk2(hn, hn1));
    }
    arrive(flags, gb, ++ep_);
    waitbar(flags, ep_);
  }
}

// ---------------- workspace layout (bytes) ----------------
#define OFF_BARE   0u
#define OFF_BARD   2048u
#define OFF_H16    4096u        // u32 [2][32][256] = 64 KB
#define OFF_CFIN   69632u       // 64 KB
#define OFF_VPART  135168u      // f32 [256][512] = 512 KB
#define OFF_AENC   659456u      // 2 MB
#define OFF_ADEC   2756608u     // 1 MB
#define OFF_WIHE   3805184u     // 1 MB
#define OFF_WIHD   4853760u     // 1 MB
#define OFF_WEB    5902336u     // 512 KB
#define OFF_WIHCP  6426624u     // 2 MB
#define OFF_OUTW   8523776u     // 32.77 MB
#define OFF_ENCXW  41291776u    // 16.78 MB  [aliased by eoP after encoder]
#define OFF_DECXW  58068992u    // 8.39 MB
#define OFF_EO     66457600u    // 4.19 MB
#define OFF_EPROJ  70651904u    // 4.19 MB
#define OFF_DECH   74846208u    // 2.10 MB -> end 76.9 MB

extern "C" void kernel_launch(void* const* d_in, const int* in_sizes, int n_in,
                              void* d_out, int out_size, void* d_ws, size_t ws_size,
                              hipStream_t stream)
{
  const int*   src     = (const int*)d_in[0];
  const int*   tgt     = (const int*)d_in[1];
  const float* enc_emb = (const float*)d_in[2];
  const float* enc_Wih = (const float*)d_in[3];
  const float* enc_Whh = (const float*)d_in[4];
  const float* enc_b   = (const float*)d_in[5];
  const float* attn_W  = (const float*)d_in[6];
  const float* attn_b  = (const float*)d_in[7];
  const float* attn_v  = (const float*)d_in[8];
  const float* dec_emb = (const float*)d_in[9];
  const float* dec_Wih = (const float*)d_in[10];
  const float* dec_Whh = (const float*)d_in[11];
  const float* dec_b   = (const float*)d_in[12];
  const float* out_W   = (const float*)d_in[13];
  const float* out_b   = (const float*)d_in[14];

  char* ws = (char*)d_ws;
  int*      barE   = (int*)(ws + OFF_BARE);
  int*      barD   = (int*)(ws + OFF_BARD);
  unsigned* h16buf = (unsigned*)(ws + OFF_H16);
  float*    cfin   = (float*)(ws + OFF_CFIN);
  float*    vpart  = (float*)(ws + OFF_VPART);
  u16*      A_enc  = (u16*)(ws + OFF_AENC);
  u16*      A_dec  = (u16*)(ws + OFF_ADEC);
  u16*      WihE   = (u16*)(ws + OFF_WIHE);
  u16*      WihD   = (u16*)(ws + OFF_WIHD);
  u16*      Web    = (u16*)(ws + OFF_WEB);
  u16*      WihCp  = (u16*)(ws + OFF_WIHCP);
  u16*      outWb  = (u16*)(ws + OFF_OUTW);
  u16*      encXW  = (u16*)(ws + OFF_ENCXW);
  u16*      eoPb   = (u16*)(ws + OFF_ENCXW);   // alias: encXW dead after encoder
  u16*      decXW  = (u16*)(ws + OFF_DECXW);
  u16*      eo_g   = (u16*)(ws + OFF_EO);
  u16*      eprojb = (u16*)(ws + OFF_EPROJ);
  u16*      dech   = (u16*)(ws + OFF_DECH);

  // zero barriers + h buffers
  (void)hipMemsetAsync(d_ws, 0, OFF_H16 + 65536, stream);

  prep_kernel<<<2048, 256, 0, stream>>>(src, tgt, enc_emb, dec_emb, enc_Wih, dec_Wih,
                                        attn_W, out_W, A_enc, A_dec, WihE, WihD, Web, WihCp, outWb);

  // encXW = emb_src @ enc_Wih^T + enc_b   (4096 x 2048 x 256) -> bf16
  gemm_nt<256, true><<<512, 256, 0, stream>>>(A_enc, WihE, enc_b, (void*)encXW, 4096, 2048);
  // decXW = emb_tgt @ dec_Wih[:, :E]^T + dec_b  (2048 x 2048 x 256) -> bf16
  gemm_nt<256, true><<<256, 256, 0, stream>>>(A_dec, WihD, dec_b, (void*)decXW, 2048, 2048);

  encoder_kernel<<<256, 256, 0, stream>>>(enc_Whh, encXW, h16buf, cfin, eo_g, barE);

  // eproj = enc_out @ W_e^T  (4096 x 512 x 512) -> bf16
  gemm_nt<512, true><<<128, 256, 0, stream>>>(eo_g, Web, nullptr, (void*)eprojb, 4096, 512);
  // eoP = enc_out @ WihCp^T  (4096 x 2048 x 512) -> bf16  (overwrites encXW; permuted cols)
  gemm_nt<512, true><<<512, 256, 0, stream>>>(eo_g, WihCp, nullptr, (void*)eoPb, 4096, 2048);

  decoder_kernel<<<256, 256, 0, stream>>>(dec_Whh, attn_W, attn_b, attn_v,
                                          eprojb, decXW, eoPb, h16buf, cfin,
                                          vpart, dech, barD);

  // out = dec_h @ out_W^T + out_b  (2048 x 32000 x 512) -> f32
  gemm_nt<512, false><<<4000, 256, 0, stream>>>(dech, outWb, out_b, d_out, 2048, 32000);
}